// Round 3
// baseline (306.233 us; speedup 1.0000x reference)
//
#include <hip/hip_runtime.h>

// Causal dilated conv1d (dilation=64, K=2) + tanh*sigmoid gate via bf16 MFMA.
// v3: LDS-free, barrier-free register streaming.
//  - Each wave independently owns 256 t of one (batch, co-group): grid
//    1024 blocks x 4 waves = 4096 waves = 4 blocks/CU, 16 waves/CU, no
//    __syncthreads anywhere (v2's barrier drains convoyed all waves).
//  - B-fragments built straight from global: lane l loads
//    x[ci=(l>>4)*8+i][t+(l&15)], 8 strided dword loads = 4 full 64B
//    sectors each. x reuse across the 4 co-group waves of a block is
//    served by L1/L2 (same addresses) instead of LDS.
//  - tap0 (t-64) operand == tap1 fragment from 4 tiles ago -> 4-deep
//    packed register ring pk[4][2] (x fetched once per wave).
//  - distance-2 software prefetch: float ring fl[2][16] is loaded 2
//    tiles ahead, packed at consume time (loads land ~2 iters early).
//  - all ring indices compile-time (full unroll) -> no scratch.
// w split hi/lo (2 MFMA terms, fp32-grade w); x single RNE bf16.
// Accumulation order identical to v2 -> bit-identical results (absmax 0.0068).
// y[b,co,t] = sum_ci w[co][ci][0]*x[b][ci][t-64] + w[co][ci][1]*x[b][ci][t]

#define B_ 16
#define C_ 64
#define T_ 16384

typedef __attribute__((ext_vector_type(8))) short short8;
typedef __attribute__((ext_vector_type(4))) float f32x4;

union Frag { short8 s; unsigned u[4]; };

__device__ __forceinline__ unsigned bf16_rne(float f) {
    unsigned u = __float_as_uint(f);
    return (u + 0x7fffu + ((u >> 16) & 1u)) >> 16;
}

__device__ __forceinline__ unsigned pack_rne(float a, float b) {
    unsigned ua = __float_as_uint(a), ub = __float_as_uint(b);
    unsigned ra = ua + 0x7fffu + ((ua >> 16) & 1u);
    unsigned rb = ub + 0x7fffu + ((ub >> 16) & 1u);
    return (ra >> 16) | (rb & 0xffff0000u);
}

__global__ __launch_bounds__(256, 4) void conv_gate_stream(
    const float* __restrict__ x,
    const float* __restrict__ w,
    float* __restrict__ out)
{
    const int tid = threadIdx.x;
    const int bid = blockIdx.x;
    // XCD-bijective swizzle (1024 wgs, 8 XCDs): consecutive strips share an
    // XCD so halo rows of neighbor strips hit the same L2.
    const int wg  = (bid & 7) * 128 + (bid >> 3);
    const int b   = wg >> 6;          // batch 0..15
    const int s   = wg & 63;          // 256-t strip 0..63
    const int t0  = s << 8;

    const int lane = tid & 63;
    const int wid  = tid >> 6;        // co-group 0..3
    const int m    = lane & 15;       // t-col within tile / co row (A)
    const int q    = lane >> 4;       // k-chunk 0..3
    const int co   = wid * 16 + m;

    const float* xb  = x + (size_t)b * C_ * T_;
    const float* xh0 = xb + (size_t)(8 * q) * T_ + m;        // ci 8q..   (k-half 0)
    const float* xh1 = xb + (size_t)(32 + 8 * q) * T_ + m;   // ci 32+8q..(k-half 1)

    // ---- per-wave w fragments (A-layout), hi/lo RNE split
    Frag wh[2][2], wl[2][2];   // [tap p][k-half h]
    #pragma unroll
    for (int h = 0; h < 2; ++h) {
        const float* wp = w + co * 128 + h * 64 + q * 16;
        float f[16];
        #pragma unroll
        for (int v4 = 0; v4 < 4; ++v4) {
            float4 t4 = *(const float4*)(wp + 4 * v4);
            f[4*v4+0] = t4.x; f[4*v4+1] = t4.y; f[4*v4+2] = t4.z; f[4*v4+3] = t4.w;
        }
        #pragma unroll
        for (int p = 0; p < 2; ++p) {
            #pragma unroll
            for (int d = 0; d < 4; ++d) {
                float e0 = f[2*(2*d)   + p];
                float e1 = f[2*(2*d+1) + p];
                unsigned h0 = bf16_rne(e0), h1 = bf16_rne(e1);
                float r0 = e0 - __uint_as_float(h0 << 16);
                float r1 = e1 - __uint_as_float(h1 << 16);
                wh[p][h].u[d] = h0 | (h1 << 16);
                wl[p][h].u[d] = bf16_rne(r0) | (bf16_rne(r1) << 16);
            }
        }
    }

    // ---- tap0 history: tiles at t0-64..t0-1, packed ring pk[jj = tile mod 4]
    Frag pk[4][2];
    if (s > 0) {
        #pragma unroll
        for (int jj = 0; jj < 4; ++jj) {
            float v0[8], v1[8];
            const float* p0 = xh0 + (t0 - 64 + 16 * jj);
            const float* p1 = xh1 + (t0 - 64 + 16 * jj);
            #pragma unroll
            for (int i = 0; i < 8; ++i) {
                v0[i] = p0[(size_t)i * T_];
                v1[i] = p1[(size_t)i * T_];
            }
            #pragma unroll
            for (int d = 0; d < 4; ++d) {
                pk[jj][0].u[d] = pack_rne(v0[2*d], v0[2*d+1]);
                pk[jj][1].u[d] = pack_rne(v1[2*d], v1[2*d+1]);
            }
        }
    } else {   // t-64 < 0: causal zero-pad
        #pragma unroll
        for (int jj = 0; jj < 4; ++jj) {
            #pragma unroll
            for (int d = 0; d < 4; ++d) { pk[jj][0].u[d] = 0u; pk[jj][1].u[d] = 0u; }
        }
    }

    // ---- prime the distance-2 float prefetch ring with tiles 0,1
    float fl[2][16];
    #pragma unroll
    for (int jj = 0; jj < 2; ++jj) {
        const float* p0 = xh0 + (t0 + 16 * jj);
        const float* p1 = xh1 + (t0 + 16 * jj);
        #pragma unroll
        for (int i = 0; i < 8; ++i) {
            fl[jj][i]     = p0[(size_t)i * T_];
            fl[jj][8 + i] = p1[(size_t)i * T_];
        }
    }

    float* ob = out + ((size_t)b * C_ + wid * 16) * T_ + t0;

    // ---- 16 tiles of 16 t, fully unrolled (static ring indices)
    #pragma unroll
    for (int j = 0; j < 16; ++j) {
        // (1) pack tile j (its loads were issued 2 iterations ago)
        Frag n0, n1;
        #pragma unroll
        for (int d = 0; d < 4; ++d) {
            n0.u[d] = pack_rne(fl[j & 1][2*d],     fl[j & 1][2*d + 1]);
            n1.u[d] = pack_rne(fl[j & 1][8 + 2*d], fl[j & 1][8 + 2*d + 1]);
        }
        // (2) issue loads for tile j+2 into the slot just freed
        if (j < 14) {
            const float* p0 = xh0 + (t0 + 16 * (j + 2));
            const float* p1 = xh1 + (t0 + 16 * (j + 2));
            #pragma unroll
            for (int i = 0; i < 8; ++i) {
                fl[j & 1][i]     = p0[(size_t)i * T_];
                fl[j & 1][8 + i] = p1[(size_t)i * T_];
            }
        }
        // (3) MFMA: tap0 (ring, t-64) then tap1 (fresh) — same order as v2
        f32x4 acc = (f32x4){0.f, 0.f, 0.f, 0.f};
        acc = __builtin_amdgcn_mfma_f32_16x16x32_bf16(wh[0][0].s, pk[j & 3][0].s, acc, 0, 0, 0);
        acc = __builtin_amdgcn_mfma_f32_16x16x32_bf16(wl[0][0].s, pk[j & 3][0].s, acc, 0, 0, 0);
        acc = __builtin_amdgcn_mfma_f32_16x16x32_bf16(wh[0][1].s, pk[j & 3][1].s, acc, 0, 0, 0);
        acc = __builtin_amdgcn_mfma_f32_16x16x32_bf16(wl[0][1].s, pk[j & 3][1].s, acc, 0, 0, 0);
        acc = __builtin_amdgcn_mfma_f32_16x16x32_bf16(wh[1][0].s, n0.s, acc, 0, 0, 0);
        acc = __builtin_amdgcn_mfma_f32_16x16x32_bf16(wl[1][0].s, n0.s, acc, 0, 0, 0);
        acc = __builtin_amdgcn_mfma_f32_16x16x32_bf16(wh[1][1].s, n1.s, acc, 0, 0, 0);
        acc = __builtin_amdgcn_mfma_f32_16x16x32_bf16(wl[1][1].s, n1.s, acc, 0, 0, 0);
        // (4) rotate: tile j becomes tap0 for tile j+4
        pk[j & 3][0] = n0;
        pk[j & 3][1] = n1;
        // (5) gate + store.  D: row(co-off)=4q+r, col(t-off)=m
        #pragma unroll
        for (int r = 0; r < 4; ++r) {
            float y = acc[r];
            y = fminf(fmaxf(y, -20.f), 20.f);
            float e   = __expf(-y);
            float e2  = e * e;
            float num = 1.f - e2;
            float den = (1.f + e) * (1.f + e2);
            ob[(size_t)(4 * q + r) * T_ + 16 * j + m] = num * __builtin_amdgcn_rcpf(den);
        }
    }
}

extern "C" void kernel_launch(void* const* d_in, const int* in_sizes, int n_in,
                              void* d_out, int out_size, void* d_ws, size_t ws_size,
                              hipStream_t stream) {
    const float* x = (const float*)d_in[0];
    const float* w = (const float*)d_in[1];
    float* out = (float*)d_out;
    conv_gate_stream<<<dim3(1024), dim3(256), 0, stream>>>(x, w, out);
}

// Round 4
// 125.723 us; speedup vs baseline: 2.4358x; 2.4358x over previous
//
#include <hip/hip_runtime.h>

// Causal dilated conv1d (dilation=64, K=2) + tanh*sigmoid gate via bf16 MFMA.
// v4 = v2 (LDS ring pipeline, best measured) + transposed-output MFMA:
//   mfma(A=x_frag, B=w_frag) -> D[t][co] instead of D[co][t].
//   A/B fragment register layouts are identical under the swap (lane&15 is
//   row-idx for A, col-idx for B; k = 8q+2d+e either way), so staging, LDS,
//   and fragment builds are byte-identical to v2. Only the epilogue changes:
//   lane (m,q) now holds 4 CONSECUTIVE t of out-row co=wid*16+m ->
//   one global_store_dwordx4 (16 B/lane) per subtile vs 4 scattered dwords.
//   Theory: all versions plateau at 2.5-2.9 TB/s with 4 B/lane accesses;
//   16 B/lane is the measured fix (fills: 6.5 TB/s; m13 float4: 6.3 TB/s).
// w split hi/lo (2 MFMA terms, fp32-grade w); x single RNE bf16.
// y[b,co,t] = sum_ci w[co][ci][0]*x[b][ci][t-64] + w[co][ci][1]*x[b][ci][t]

#define B_ 16
#define C_ 64
#define T_ 16384
#define RING 128          // ring rows (power of 2), row = 64 bf16 = 128 B

typedef __attribute__((ext_vector_type(8))) short short8;
typedef __attribute__((ext_vector_type(4))) float f32x4;

union Frag { short8 s; unsigned u[4]; };

__device__ __forceinline__ unsigned bf16_rne(float f) {
    unsigned u = __float_as_uint(f);
    return (u + 0x7fffu + ((u >> 16) & 1u)) >> 16;
}

__device__ __forceinline__ unsigned pack_rne(float a, float b) {
    unsigned ua = __float_as_uint(a), ub = __float_as_uint(b);
    unsigned ra = ua + 0x7fffu + ((ua >> 16) & 1u);
    unsigned rb = ub + 0x7fffu + ((ub >> 16) & 1u);
    return (ra >> 16) | (rb & 0xffff0000u);
}

// Epilogue for chunk KK: lane (m,q) holds rows t = 4q+r, col co=wid*16+m of
// the transposed D tile. One float4 store per subtile s.
#define EPILOGUE(A, KK)                                                     \
    _Pragma("unroll")                                                       \
    for (int s = 0; s < 4; ++s) {                                           \
        float4 o4;                                                          \
        _Pragma("unroll")                                                   \
        for (int r = 0; r < 4; ++r) {                                       \
            float y = (A)[s][r];                                            \
            y = fminf(fmaxf(y, -20.f), 20.f);                               \
            float e   = __expf(-y);                                         \
            float e2  = e * e;                                              \
            float num = 1.f - e2;                                           \
            float den = (1.f + e) * (1.f + e2);                             \
            ((float*)&o4)[r] = num * __builtin_amdgcn_rcpf(den);            \
        }                                                                   \
        *(float4*)(ob + (KK) * 64 + 16 * s + 4 * q) = o4;                   \
    }

__global__ __launch_bounds__(256, 4) void conv_gate_ring4(
    const float* __restrict__ x,
    const float* __restrict__ w,
    float* __restrict__ out)
{
    __shared__ unsigned short xs[RING * 64];   // 16384 B

    const int tid = threadIdx.x;
    const int bid = blockIdx.x;
    // XCD-bijective swizzle (1024 wgs, 8 XCDs): contiguous segs share an XCD
    // so halo rows of neighbor segments hit the same L2.
    const int wg  = (bid & 7) * 128 + (bid >> 3);
    const int b   = wg >> 6;          // batch
    const int seg = wg & 63;          // which 256-t segment
    const int t0  = seg << 8;
    const float* xb = x + (size_t)b * C_ * T_;

    // ---- prologue: issue loads for rows [t0-64, t0+64)  (ring slots (rr+64)&127)
    // task = (rr 0..127, c8 0..7); lanes consecutive in rr -> 256B coalesced.
    float pv[4][8];
    #pragma unroll
    for (int it = 0; it < 4; ++it) {
        const int task = it * 256 + tid;
        const int rr   = task & 127;
        const int c8   = task >> 7;          // 0..7
        const int g    = t0 - 64 + rr;
        if (g >= 0) {
            const float* xp = xb + (size_t)(8 * c8) * T_ + g;
            #pragma unroll
            for (int i = 0; i < 8; ++i) pv[it][i] = xp[(size_t)i * T_];
        } else {
            #pragma unroll
            for (int i = 0; i < 8; ++i) pv[it][i] = 0.f;
        }
    }

    // ---- per-wave w fragments, hi/lo RNE split. Same bytes serve as the
    // B-operand (B[k][co]: col=lane&15=co, k=8q+2d+e) that served as A in v2.
    const int lane = tid & 63;
    const int wid  = tid >> 6;
    const int m    = lane & 15;
    const int q    = lane >> 4;
    const int co   = wid * 16 + m;

    Frag wh[2][2], wl[2][2];   // [tap p][k-half h]
    #pragma unroll
    for (int h = 0; h < 2; ++h) {
        const float* wp = w + co * 128 + h * 64 + q * 16;
        float f[16];
        #pragma unroll
        for (int v4 = 0; v4 < 4; ++v4) {
            float4 t4 = *(const float4*)(wp + 4 * v4);
            f[4*v4+0] = t4.x; f[4*v4+1] = t4.y; f[4*v4+2] = t4.z; f[4*v4+3] = t4.w;
        }
        #pragma unroll
        for (int p = 0; p < 2; ++p) {
            #pragma unroll
            for (int d = 0; d < 4; ++d) {
                float e0 = f[2*(2*d)   + p];
                float e1 = f[2*(2*d+1) + p];
                unsigned h0 = bf16_rne(e0), h1 = bf16_rne(e1);
                float r0 = e0 - __uint_as_float(h0 << 16);
                float r1 = e1 - __uint_as_float(h1 << 16);
                wh[p][h].u[d] = h0 | (h1 << 16);
                wl[p][h].u[d] = bf16_rne(r0) | (bf16_rne(r1) << 16);
            }
        }
    }

    // ---- prologue pack + ring write
    #pragma unroll
    for (int it = 0; it < 4; ++it) {
        const int task = it * 256 + tid;
        const int rr   = task & 127;
        const int c8   = task >> 7;
        unsigned p0 = pack_rne(pv[it][0], pv[it][1]);
        unsigned p1 = pack_rne(pv[it][2], pv[it][3]);
        unsigned p2 = pack_rne(pv[it][4], pv[it][5]);
        unsigned p3 = pack_rne(pv[it][6], pv[it][7]);
        const int slot = (rr + 64) & 127;                    // slot = g & 127
        const int so   = slot * 64 + ((c8 ^ (rr & 7)) * 8);  // rr&7 == g&7
        *(uint4*)(&xs[so]) = make_uint4(p0, p1, p2, p3);
    }

    const int n   = m;
    const int swb = n & 7;
    // transposed store base: lane's out row is co = wid*16 + m
    float* ob = out + ((size_t)b * C_ + wid * 16 + m) * T_ + t0;

    f32x4 acc2[2][4];          // double accumulator: epilogue(k-1) overlaps chunk k

    __syncthreads();

    // ---- 4 chunks of 64 t. Chunk k computes from ring window [c0-64, c0+64),
    // c0 = t0 + 64k; rows 16u+n-64: u<4 -> tap0 of subtile u, u>=4 -> tap1 of u-4.
    #pragma unroll
    for (int k = 0; k < 4; ++k) {
        // (1) prefetch next chunk's rows [t0 + 64(k+1), +64) into registers
        float v[2][8];
        if (k < 3) {
            #pragma unroll
            for (int it = 0; it < 2; ++it) {
                const int task = it * 256 + tid;
                const int rr = task & 63, c8 = task >> 6;
                const float* xp = xb + (size_t)(8 * c8) * T_ + (t0 + 64 * (k + 1) + rr);
                #pragma unroll
                for (int i = 0; i < 8; ++i) v[it][i] = xp[(size_t)i * T_];
            }
        }

        // (2) deferred epilogue of chunk k-1: stores drain during this compute
        if (k > 0) { EPILOGUE(acc2[(k & 1) ^ 1], k - 1); }

        // (3) compute chunk k — transposed: A = x frag, B = w frag
        f32x4* acc = acc2[k & 1];
        #pragma unroll
        for (int s = 0; s < 4; ++s) acc[s] = (f32x4){0.f, 0.f, 0.f, 0.f};
        const int kb = ((k & 1) ^ 1) << 6;   // (c0-64) & 127
        #pragma unroll
        for (int u = 0; u < 8; ++u) {
            const int rbase = ((kb + 16 * u + n) & 127) * 64;
            Frag f0, f1;
            f0.s = *(const short8*)(&xs[rbase + ((q ^ swb) * 8)]);        // ci 8q..
            f1.s = *(const short8*)(&xs[rbase + (((4 + q) ^ swb) * 8)]);  // ci 32+8q..
            if (u < 4) {
                acc[u] = __builtin_amdgcn_mfma_f32_16x16x32_bf16(f0.s, wh[0][0].s, acc[u], 0, 0, 0);
                acc[u] = __builtin_amdgcn_mfma_f32_16x16x32_bf16(f0.s, wl[0][0].s, acc[u], 0, 0, 0);
                acc[u] = __builtin_amdgcn_mfma_f32_16x16x32_bf16(f1.s, wh[0][1].s, acc[u], 0, 0, 0);
                acc[u] = __builtin_amdgcn_mfma_f32_16x16x32_bf16(f1.s, wl[0][1].s, acc[u], 0, 0, 0);
            } else {
                const int s2 = u - 4;
                acc[s2] = __builtin_amdgcn_mfma_f32_16x16x32_bf16(f0.s, wh[1][0].s, acc[s2], 0, 0, 0);
                acc[s2] = __builtin_amdgcn_mfma_f32_16x16x32_bf16(f0.s, wl[1][0].s, acc[s2], 0, 0, 0);
                acc[s2] = __builtin_amdgcn_mfma_f32_16x16x32_bf16(f1.s, wh[1][1].s, acc[s2], 0, 0, 0);
                acc[s2] = __builtin_amdgcn_mfma_f32_16x16x32_bf16(f1.s, wl[1][1].s, acc[s2], 0, 0, 0);
            }
        }

        if (k < 3) {
            __syncthreads();   // window-k reads done (also drains prefetch loads)

            // (4) pack + write next chunk into the 64 slots just freed
            #pragma unroll
            for (int it = 0; it < 2; ++it) {
                const int task = it * 256 + tid;
                const int rr = task & 63, c8 = task >> 6;
                unsigned p0 = pack_rne(v[it][0], v[it][1]);
                unsigned p1 = pack_rne(v[it][2], v[it][3]);
                unsigned p2 = pack_rne(v[it][4], v[it][5]);
                unsigned p3 = pack_rne(v[it][6], v[it][7]);
                const int slot = (64 * (k + 1) + rr) & 127;
                const int so   = slot * 64 + ((c8 ^ (rr & 7)) * 8);
                *(uint4*)(&xs[so]) = make_uint4(p0, p1, p2, p3);
            }

            __syncthreads();   // ring writes visible before next compute
        }
    }

    // epilogue of the last chunk
    EPILOGUE(acc2[1], 3);
}

extern "C" void kernel_launch(void* const* d_in, const int* in_sizes, int n_in,
                              void* d_out, int out_size, void* d_ws, size_t ws_size,
                              hipStream_t stream) {
    const float* x = (const float*)d_in[0];
    const float* w = (const float*)d_in[1];
    float* out = (float*)d_out;
    conv_gate_ring4<<<dim3(1024), dim3(256), 0, stream>>>(x, w, out);
}